// Round 6
// baseline (531.689 us; speedup 1.0000x reference)
//
#include <hip/hip_runtime.h>
#include <cmath>

// x[32768, 256] fp32, codebook[1024, 256] fp32. Outputs fp32 flat:
// loss(1), z_q(8388608), perplexity(1), indices(32768)
#define NROWS 32768
#define DDIM  256
#define KCB   1024

constexpr float TAU = 0.35f;   // fp16-path margin for fp64 recheck (validated r4/r5)

typedef _Float16 half8 __attribute__((ext_vector_type(8)));
typedef _Float16 half4 __attribute__((ext_vector_type(4)));
typedef float floatx4 __attribute__((ext_vector_type(4)));

__global__ void init_kernel(double* __restrict__ sumsq, int* __restrict__ sumidx) {
  *sumsq = 0.0;
  *sumidx = 0;
}

// Exact codebook norms (fp64 -> fp32) and (if ws allows) fp16 codebook copy.
template<bool CVT>
__global__ __launch_bounds__(64) void prep_kernel(const float* __restrict__ cb,
                                                  float* __restrict__ cn,
                                                  _Float16* __restrict__ cbh) {
  const int k = blockIdx.x, lane = threadIdx.x;
  float4 v = *(const float4*)(cb + (size_t)k * DDIM + lane * 4);
  double s = (double)v.x * v.x + (double)v.y * v.y
           + (double)v.z * v.z + (double)v.w * v.w;
  #pragma unroll
  for (int off = 32; off; off >>= 1) s += __shfl_down(s, off);
  if (lane == 0) cn[k] = (float)s;
  if constexpr (CVT) {
    half4 h;
    h[0] = (_Float16)v.x; h[1] = (_Float16)v.y;
    h[2] = (_Float16)v.z; h[3] = (_Float16)v.w;
    *(half4*)&cbh[(size_t)k * DDIM + lane * 4] = h;
  }
}

// One block = ONE wave = 16 rows. No LDS / no barriers in the K-loop:
// A-frags (own x rows, fp16) live in 32 VGPRs; B-frags stream from the
// L2-resident fp16 codebook, 1:1 interleaved with MFMA. dist = cn - 2*dot.
// Rows with fp32 margin < TAU get an exact in-block fp64 re-scan.
template<bool H>
__global__ __launch_bounds__(64, 4) void fused_kernel(
    const float* __restrict__ x,
    const float* __restrict__ cb,
    const _Float16* __restrict__ cbh,
    const float* __restrict__ cn,
    float* __restrict__ zq_out,
    float* __restrict__ idx_out,
    double* __restrict__ sumsq,
    int* __restrict__ sumidx) {
  __shared__ int   bidx[16];
  __shared__ float marg[16];
  __shared__ __align__(16) float xrow[DDIM];
  __shared__ int   flist[16];
  __shared__ int   nflag;

  const int lane = threadIdx.x;
  const int q = lane >> 4;       // quad
  const int tx = lane & 15;
  const int row0 = blockIdx.x * 16;

  // ---- A fragments: lane holds x[row0+tx][s*32 + q*8 .. +7] as fp16 ----
  half8 a[8];
  {
    const float* xp = x + (size_t)(row0 + tx) * DDIM + q * 8;
    #pragma unroll
    for (int s = 0; s < 8; ++s) {
      float4 v0 = *(const float4*)(xp + s * 32);
      float4 v1 = *(const float4*)(xp + s * 32 + 4);
      half8 h;
      h[0] = (_Float16)v0.x; h[1] = (_Float16)v0.y;
      h[2] = (_Float16)v0.z; h[3] = (_Float16)v0.w;
      h[4] = (_Float16)v1.x; h[5] = (_Float16)v1.y;
      h[6] = (_Float16)v1.z; h[7] = (_Float16)v1.w;
      a[s] = h;
    }
  }

  float minv[4], minv2[4];
  int mini[4];
  #pragma unroll
  for (int r = 0; r < 4; ++r) { minv[r] = INFINITY; minv2[r] = INFINITY; mini[r] = 0; }

  for (int kt = 0; kt < 16; ++kt) {
    floatx4 acc[4];
    #pragma unroll
    for (int c = 0; c < 4; ++c) acc[c] = (floatx4){0.f, 0.f, 0.f, 0.f};

    #pragma unroll
    for (int s = 0; s < 8; ++s) {
      #pragma unroll
      for (int c = 0; c < 4; ++c) {
        half8 b;
        if constexpr (H) {
          b = *(const half8*)&cbh[(size_t)(kt * 64 + c * 16 + tx) * DDIM + s * 32 + q * 8];
        } else {
          const float* p = cb + (size_t)(kt * 64 + c * 16 + tx) * DDIM + s * 32 + q * 8;
          float4 v0 = *(const float4*)p, v1 = *(const float4*)(p + 4);
          b[0] = (_Float16)v0.x; b[1] = (_Float16)v0.y;
          b[2] = (_Float16)v0.z; b[3] = (_Float16)v0.w;
          b[4] = (_Float16)v1.x; b[5] = (_Float16)v1.y;
          b[6] = (_Float16)v1.z; b[7] = (_Float16)v1.w;
        }
        acc[c] = __builtin_amdgcn_mfma_f32_16x16x32_f16(a[s], b, acc[c], 0, 0, 0);
      }
    }

    // epilogue: C/D layout col=lane&15, row=q*4+reg
    #pragma unroll
    for (int c = 0; c < 4; ++c) {
      int col = kt * 64 + c * 16 + tx;
      float cnv = cn[col];
      #pragma unroll
      for (int r = 0; r < 4; ++r) {
        float dist = cnv - 2.f * acc[c][r];
        if (dist < minv[r]) {
          minv2[r] = minv[r];
          minv[r] = dist; mini[r] = col;
        } else if (dist < minv2[r]) {
          minv2[r] = dist;
        }
      }
    }
  }

  // merge (best, idx, second) across the 16 tx-lanes of each quad
  #pragma unroll
  for (int off = 8; off; off >>= 1) {
    #pragma unroll
    for (int r = 0; r < 4; ++r) {
      float ov  = __shfl_down(minv[r],  off, 16);
      int   oi  = __shfl_down(mini[r],  off, 16);
      float ov2 = __shfl_down(minv2[r], off, 16);
      if (ov < minv[r] || (ov == minv[r] && oi < mini[r])) {
        minv2[r] = fminf(minv[r], ov2);
        minv[r] = ov; mini[r] = oi;
      } else {
        minv2[r] = fminf(minv2[r], ov);
      }
    }
  }
  if (tx == 0) {
    #pragma unroll
    for (int r = 0; r < 4; ++r) {
      bidx[q * 4 + r] = mini[r];
      marg[q * 4 + r] = minv2[r] - minv[r];
    }
  }
  if (lane == 0) nflag = 0;
  __syncthreads();

  if (lane < 16 && marg[lane] < TAU) {
    int p = atomicAdd(&nflag, 1);
    flist[p] = lane;
  }
  __syncthreads();

  // exact fp64 re-scan of all 1024 candidates for flagged rows (~2%)
  for (int f = 0; f < nflag; ++f) {
    int r = flist[f];
    *(float4*)&xrow[lane * 4] =
        *(const float4*)(x + (size_t)(row0 + r) * DDIM + lane * 4);
    __syncthreads();
    double bestd = 1e300; int bi = 0;
    for (int j = 0; j < 16; ++j) {
      int e = j * 64 + lane;               // ascending per lane
      const float* crow = cb + (size_t)e * DDIM;
      double s = 0.0;
      for (int d = 0; d < DDIM; d += 4) {
        float4 cv = *(const float4*)(crow + d);
        double d0 = (double)xrow[d + 0] - (double)cv.x; s = fma(d0, d0, s);
        double d1 = (double)xrow[d + 1] - (double)cv.y; s = fma(d1, d1, s);
        double d2 = (double)xrow[d + 2] - (double)cv.z; s = fma(d2, d2, s);
        double d3 = (double)xrow[d + 3] - (double)cv.w; s = fma(d3, d3, s);
      }
      if (s < bestd) { bestd = s; bi = e; }
    }
    #pragma unroll
    for (int off = 32; off; off >>= 1) {
      double ov = __shfl_down(bestd, off);
      int oi = __shfl_down(bi, off);
      if (ov < bestd || (ov == bestd && oi < bi)) { bestd = ov; bi = oi; }
    }
    if (lane == 0) bidx[r] = bi;
    __syncthreads();
  }

  if (lane < 16) idx_out[row0 + lane] = (float)bidx[lane];

  // ---- gather: z_q rows (exact fp32 copies) + loss partial ----
  float lsum = 0.f;
  #pragma unroll 4
  for (int r = 0; r < 16; ++r) {
    int k = bidx[r];
    float4 cv = *(const float4*)(cb + (size_t)k * DDIM + lane * 4);
    float4 xv = *(const float4*)(x + (size_t)(row0 + r) * DDIM + lane * 4);
    float d0 = cv.x - xv.x, d1 = cv.y - xv.y, d2 = cv.z - xv.z, d3 = cv.w - xv.w;
    lsum = fmaf(d0, d0, lsum); lsum = fmaf(d1, d1, lsum);
    lsum = fmaf(d2, d2, lsum); lsum = fmaf(d3, d3, lsum);
    *(float4*)(zq_out + (size_t)(row0 + r) * DDIM + lane * 4) = cv;
  }
  #pragma unroll
  for (int off = 32; off; off >>= 1) lsum += __shfl_down(lsum, off);
  if (lane == 0) {
    atomicAdd(sumsq, (double)lsum);
    int si = 0;
    #pragma unroll
    for (int r = 0; r < 16; ++r) si += bidx[r];
    atomicAdd(sumidx, si);
  }
}

__global__ void finalize_kernel(const double* __restrict__ sumsq,
                                const int* __restrict__ sumidx,
                                float* __restrict__ out_loss,
                                float* __restrict__ out_perp) {
  // loss = mean(sg(zq)-x)^2 + 0.25*mean(zq-sg(x))^2 = 1.25 * MSE (fwd equal)
  double loss = 1.25 * (*sumsq) / 8388608.0;
  double e_min = (double)(*sumidx) / 32768.0;      // scalar mean of indices
  double perp = exp(-e_min * log(e_min + 1e-10));  // underflows to 0
  *out_loss = (float)loss;
  *out_perp = (float)perp;
}

extern "C" void kernel_launch(void* const* d_in, const int* in_sizes, int n_in,
                              void* d_out, int out_size, void* d_ws, size_t ws_size,
                              hipStream_t stream) {
  const float* x  = (const float*)d_in[0];   // [32768, 256] fp32
  const float* cb = (const float*)d_in[1];   // [1024, 256] fp32
  float* out = (float*)d_out;
  float* out_loss = out;                  // [0]
  float* out_zq   = out + 1;              // [1 .. 8388608]
  float* out_perp = out + 1 + 8388608;    // [8388609]
  float* out_idx  = out + 2 + 8388608;    // [8388610 ..]

  double*   sumsq  = (double*)d_ws;
  int*      sumidx = (int*)((char*)d_ws + 8);
  float*    cn     = (float*)((char*)d_ws + 16);     // 4 KB
  _Float16* cbh    = (_Float16*)((char*)d_ws + 8192); // 512 KB (optional)

  // ws_size is launch-invariant, so this branch is deterministic across calls.
  const bool useH = ws_size >= (size_t)(8192 + KCB * DDIM * 2);

  hipLaunchKernelGGL(init_kernel, dim3(1), dim3(1), 0, stream, sumsq, sumidx);
  if (useH) {
    hipLaunchKernelGGL(prep_kernel<true>, dim3(KCB), dim3(64), 0, stream, cb, cn, cbh);
    hipLaunchKernelGGL(fused_kernel<true>, dim3(NROWS / 16), dim3(64), 0, stream,
                       x, cb, cbh, cn, out_zq, out_idx, sumsq, sumidx);
  } else {
    hipLaunchKernelGGL(prep_kernel<false>, dim3(KCB), dim3(64), 0, stream, cb, cn, cbh);
    hipLaunchKernelGGL(fused_kernel<false>, dim3(NROWS / 16), dim3(64), 0, stream,
                       x, cb, cbh, cn, out_zq, out_idx, sumsq, sumidx);
  }
  hipLaunchKernelGGL(finalize_kernel, dim3(1), dim3(1), 0, stream,
                     sumsq, sumidx, out_loss, out_perp);
}